// Round 4
// baseline (1484.158 us; speedup 1.0000x reference)
//
#include <hip/hip_runtime.h>

typedef _Float16 f16;
typedef __attribute__((ext_vector_type(8))) _Float16 f16x8;
typedef __attribute__((ext_vector_type(4))) float f32x4;

#define BT   131072
#define DD   512
#define TM   32
#define MEFF 96
#define NBLK (BT / TM)  // 4096

// swizzled LDS fp16 tile: byte = row*1024 + (colbyte ^ ((row&7)<<4))
__device__ __forceinline__ void stA(char* ab, int row, int colbyte, float v) {
    *(f16*)(ab + row * 1024 + (colbyte ^ ((row & 7) << 4))) = (f16)v;
}
__device__ __forceinline__ f16x8 ldA8(const char* ab, int row, int kbyte) {
    return *(const f16x8*)(ab + row * 1024 + (kbyte ^ ((row & 7) << 4)));
}

// Pack W1..W3 (512x512 fp32 row-major) into MFMA B-fragment order fp16:
// frag f = (l*16+sk)*32 + nsub ; lane l: n = nsub*16+(lane&15), k = sk*32+(lane>>4)*8 .. +8
__global__ void prep_w(const float* __restrict__ W1, const float* __restrict__ W2,
                       const float* __restrict__ W3, f16* __restrict__ wp) {
    int tid = blockIdx.x * 256 + threadIdx.x;
    if (tid >= 3 * 16 * 32 * 64) return;
    int lane = tid & 63;
    int frag = tid >> 6;
    int nsub = frag & 31;
    int sk   = (frag >> 5) & 15;
    int l    = frag >> 9;
    const float* W = (l == 0) ? W1 : (l == 1) ? W2 : W3;
    int n = nsub * 16 + (lane & 15);
    int k = sk * 32 + (lane >> 4) * 8;
    const float* p = W + n * DD + k;
    f16x8 o;
    #pragma unroll
    for (int j = 0; j < 8; ++j) o[j] = (f16)p[j];
    ((f16x8*)wp)[tid] = o;
}

#define ACC(m, n) acc_##m##_##n

#define MF4(m, Am, Bq0, Bq1, Bq2, Bq3)                                        \
    ACC(m,0) = __builtin_amdgcn_mfma_f32_16x16x32_f16(Am, Bq0, ACC(m,0),0,0,0); \
    ACC(m,1) = __builtin_amdgcn_mfma_f32_16x16x32_f16(Am, Bq1, ACC(m,1),0,0,0); \
    ACC(m,2) = __builtin_amdgcn_mfma_f32_16x16x32_f16(Am, Bq2, ACC(m,2),0,0,0); \
    ACC(m,3) = __builtin_amdgcn_mfma_f32_16x16x32_f16(Am, Bq3, ACC(m,3),0,0,0);

#define ROW1(m, skc, Bq0, Bq1, Bq2, Bq3)                                       \
    { f16x8 Am = *(const f16x8*)(ab + ((m)*16 + l15)*1024 +                    \
                                 ((((skc)*64) + kx) ^ swz));                   \
      MF4(m, Am, Bq0, Bq1, Bq2, Bq3) }

#define ROWS6(skc, Bq0, Bq1, Bq2, Bq3)                                         \
    ROW1(0, skc, Bq0, Bq1, Bq2, Bq3) ROW1(1, skc, Bq0, Bq1, Bq2, Bq3)          \
    ROW1(2, skc, Bq0, Bq1, Bq2, Bq3) ROW1(3, skc, Bq0, Bq1, Bq2, Bq3)          \
    ROW1(4, skc, Bq0, Bq1, Bq2, Bq3) ROW1(5, skc, Bq0, Bq1, Bq2, Bq3)

#define CVT1(Rn, skc, n)                                                       \
    { const float* q = Wl + (size_t)(wv*64 + (n)*16 + l15)*DD + (skc)*32 + g16*8; \
      float4 u0 = *(const float4*)q; float4 u1 = *(const float4*)(q + 4);      \
      f16x8 r;                                                                 \
      r[0]=(f16)u0.x; r[1]=(f16)u0.y; r[2]=(f16)u0.z; r[3]=(f16)u0.w;          \
      r[4]=(f16)u1.x; r[5]=(f16)u1.y; r[6]=(f16)u1.z; r[7]=(f16)u1.w; Rn = r; }

#define LOADB(R0, R1, R2, R3, skc)                                             \
    if constexpr (PREP) {                                                      \
        R0 = wB[((skc)*32 + 0)*64]; R1 = wB[((skc)*32 + 1)*64];                \
        R2 = wB[((skc)*32 + 2)*64]; R3 = wB[((skc)*32 + 3)*64];                \
    } else { CVT1(R0,skc,0) CVT1(R1,skc,1) CVT1(R2,skc,2) CVT1(R3,skc,3) }

// epilogue: one accumulator element -> h (LDS) + both tangent rows, sigma inline
#define EPIR(AH, AX, AY, m, n, r, F)                                           \
    { float z  = AH.F + bias##n;                                               \
      float aa = fabsf(z);                                                     \
      float e  = __expf(-20.f * aa);                                           \
      float d  = 1.f + e;                                                      \
      float rd = __builtin_amdgcn_rcpf(d);                                     \
      float h  = fmaxf(z, 0.f) + __logf(d) * 0.05f;                            \
      float sg = (z > 0.f ? 1.f : e) * rd;                                     \
      int  row = (m)*16 + g16*4 + (r);                                         \
      int  cb  = (wv*64 + (n)*16 + l15) * 2;                                   \
      stA(ab, row,      cb, h);                                                \
      stA(ab, row + 32, cb, sg * AX.F);                                        \
      stA(ab, row + 64, cb, sg * AY.F); }

#define EPIN(AH, AX, AY, m, n)                                                 \
    EPIR(AH, AX, AY, m, n, 0, x) EPIR(AH, AX, AY, m, n, 1, y)                  \
    EPIR(AH, AX, AY, m, n, 2, z) EPIR(AH, AX, AY, m, n, 3, w)

template<bool PREP>
__global__ __launch_bounds__(512) void mlp_fused(
    const float* __restrict__ tx,
    const float* __restrict__ W0, const float* __restrict__ b0v,
    const float* __restrict__ W1, const float* __restrict__ b1v,
    const float* __restrict__ W2, const float* __restrict__ b2v,
    const float* __restrict__ W3, const float* __restrict__ b3v,
    const float* __restrict__ W4, const float* __restrict__ b4v,
    const f16* __restrict__ wp, float* __restrict__ out)
{
    __shared__ __align__(16) short abuf_s[MEFF * DD];  // 96 KB fp16, swizzled
    __shared__ float txb[TM * 3];
    char* ab = (char*)abuf_s;

    const int tid  = threadIdx.x;
    const int lane = tid & 63;
    const int wv   = tid >> 6;   // 0..7, owns cols [wv*64, wv*64+64)
    const int g16  = lane >> 4;
    const int l15  = lane & 15;
    const int swz  = (l15 & 7) << 4;
    const int kx   = g16 * 16;
    const long s0  = (long)blockIdx.x * TM;

    if (tid < TM * 3) txb[tid] = tx[s0 * 3 + tid];
    __syncthreads();

    // ---- layer 0 (K=3, fp32 VALU); rows: h | sg*W0[:,1] | sg*W0[:,2]
    {
        int n = tid;
        float w0 = W0[n * 3 + 0], w1 = W0[n * 3 + 1], w2 = W0[n * 3 + 2], bb = b0v[n];
        #pragma unroll 4
        for (int s = 0; s < TM; ++s) {
            float z  = fmaf(w0, txb[s * 3], fmaf(w1, txb[s * 3 + 1], fmaf(w2, txb[s * 3 + 2], bb)));
            float aa = fabsf(z);
            float e  = __expf(-20.f * aa);
            float d  = 1.f + e;
            float h  = fmaxf(z, 0.f) + __logf(d) * 0.05f;
            float sg = (z > 0.f ? 1.f : e) * __builtin_amdgcn_rcpf(d);
            stA(ab, s,          n * 2, h);
            stA(ab, TM + s,     n * 2, sg * w1);
            stA(ab, 2 * TM + s, n * 2, sg * w2);
        }
    }
    __syncthreads();

    // ---- layers 1..3: fused GEMM over M_eff=96 rows (h + 2 tangents), N=K=512
    for (int l = 0; l < 3; ++l) {
        const float* Wl = (l == 0) ? W1 : (l == 1) ? W2 : W3;
        const float* bl = (l == 0) ? b1v : (l == 1) ? b2v : b3v;
        const f16x8* wB = (const f16x8*)wp + (size_t)l * (16 * 32 * 64)
                        + (size_t)(wv * 4) * 64 + lane;

        f32x4 acc_0_0, acc_0_1, acc_0_2, acc_0_3;
        f32x4 acc_1_0, acc_1_1, acc_1_2, acc_1_3;
        f32x4 acc_2_0, acc_2_1, acc_2_2, acc_2_3;
        f32x4 acc_3_0, acc_3_1, acc_3_2, acc_3_3;
        f32x4 acc_4_0, acc_4_1, acc_4_2, acc_4_3;
        f32x4 acc_5_0, acc_5_1, acc_5_2, acc_5_3;
        const f32x4 zz = {0.f, 0.f, 0.f, 0.f};
        acc_0_0=zz; acc_0_1=zz; acc_0_2=zz; acc_0_3=zz;
        acc_1_0=zz; acc_1_1=zz; acc_1_2=zz; acc_1_3=zz;
        acc_2_0=zz; acc_2_1=zz; acc_2_2=zz; acc_2_3=zz;
        acc_3_0=zz; acc_3_1=zz; acc_3_2=zz; acc_3_3=zz;
        acc_4_0=zz; acc_4_1=zz; acc_4_2=zz; acc_4_3=zz;
        acc_5_0=zz; acc_5_1=zz; acc_5_2=zz; acc_5_3=zz;

        f16x8 B0, B1, B2, B3, C0, C1, C2, C3;
        LOADB(B0, B1, B2, B3, 0)
        #pragma unroll
        for (int sk = 0; sk < 16; sk += 2) {
            LOADB(C0, C1, C2, C3, sk + 1)
            ROWS6(sk, B0, B1, B2, B3)
            if (sk + 2 < 16) { LOADB(B0, B1, B2, B3, sk + 2) }
            ROWS6(sk + 1, C0, C1, C2, C3)
        }

        __syncthreads();  // all waves done reading abuf

        float bias0 = bl[wv * 64 + 0 * 16 + l15];
        float bias1 = bl[wv * 64 + 1 * 16 + l15];
        float bias2 = bl[wv * 64 + 2 * 16 + l15];
        float bias3 = bl[wv * 64 + 3 * 16 + l15];

        EPIN(acc_0_0, acc_2_0, acc_4_0, 0, 0)
        EPIN(acc_0_1, acc_2_1, acc_4_1, 0, 1)
        EPIN(acc_0_2, acc_2_2, acc_4_2, 0, 2)
        EPIN(acc_0_3, acc_2_3, acc_4_3, 0, 3)
        EPIN(acc_1_0, acc_3_0, acc_5_0, 1, 0)
        EPIN(acc_1_1, acc_3_1, acc_5_1, 1, 1)
        EPIN(acc_1_2, acc_3_2, acc_5_2, 1, 2)
        EPIN(acc_1_3, acc_3_3, acc_5_3, 1, 3)
        __syncthreads();
    }

    // ---- final layer (fp32 VALU dots): p = W4[1].h4 + b4[1]; u = (ds/dy, -ds/dx)
    {
        const int kb = lane * 8;
        float ws0 = W4[kb+0], ws1 = W4[kb+1], ws2 = W4[kb+2], ws3 = W4[kb+3];
        float ws4 = W4[kb+4], ws5 = W4[kb+5], ws6 = W4[kb+6], ws7 = W4[kb+7];
        float wp0 = W4[DD+kb+0], wp1 = W4[DD+kb+1], wp2 = W4[DD+kb+2], wp3 = W4[DD+kb+3];
        float wp4 = W4[DD+kb+4], wp5 = W4[DD+kb+5], wp6 = W4[DD+kb+6], wp7 = W4[DD+kb+7];
        float bp = b4v[1];
        #pragma unroll
        for (int i = 0; i < 4; ++i) {
            int s = wv * 4 + i;
            f16x8 hh = ldA8(ab, s,      lane * 16);
            f16x8 hx = ldA8(ab, 32 + s, lane * 16);
            f16x8 hy = ldA8(ab, 64 + s, lane * 16);
            float dy, dx, dp;
            dy = fmaf(ws0, (float)hy[0], 0.f);  dx = fmaf(ws0, (float)hx[0], 0.f);  dp = fmaf(wp0, (float)hh[0], 0.f);
            dy = fmaf(ws1, (float)hy[1], dy);   dx = fmaf(ws1, (float)hx[1], dx);   dp = fmaf(wp1, (float)hh[1], dp);
            dy = fmaf(ws2, (float)hy[2], dy);   dx = fmaf(ws2, (float)hx[2], dx);   dp = fmaf(wp2, (float)hh[2], dp);
            dy = fmaf(ws3, (float)hy[3], dy);   dx = fmaf(ws3, (float)hx[3], dx);   dp = fmaf(wp3, (float)hh[3], dp);
            dy = fmaf(ws4, (float)hy[4], dy);   dx = fmaf(ws4, (float)hx[4], dx);   dp = fmaf(wp4, (float)hh[4], dp);
            dy = fmaf(ws5, (float)hy[5], dy);   dx = fmaf(ws5, (float)hx[5], dx);   dp = fmaf(wp5, (float)hh[5], dp);
            dy = fmaf(ws6, (float)hy[6], dy);   dx = fmaf(ws6, (float)hx[6], dx);   dp = fmaf(wp6, (float)hh[6], dp);
            dy = fmaf(ws7, (float)hy[7], dy);   dx = fmaf(ws7, (float)hx[7], dx);   dp = fmaf(wp7, (float)hh[7], dp);
            #pragma unroll
            for (int mk = 1; mk < 64; mk <<= 1) {
                dy += __shfl_xor(dy, mk);
                dx += __shfl_xor(dx, mk);
                dp += __shfl_xor(dp, mk);
            }
            if (lane == 0) {
                float* o = out + (s0 + s) * 3;
                o[0] = dy;        // ds/dy
                o[1] = -dx;       // -ds/dx
                o[2] = dp + bp;   // pressure
            }
        }
    }
}

extern "C" void kernel_launch(void* const* d_in, const int* in_sizes, int n_in,
                              void* d_out, int out_size, void* d_ws, size_t ws_size,
                              hipStream_t stream) {
    const float* tx = (const float*)d_in[0];
    const float* W0 = (const float*)d_in[1]; const float* b0 = (const float*)d_in[2];
    const float* W1 = (const float*)d_in[3]; const float* b1 = (const float*)d_in[4];
    const float* W2 = (const float*)d_in[5]; const float* b2 = (const float*)d_in[6];
    const float* W3 = (const float*)d_in[7]; const float* b3 = (const float*)d_in[8];
    const float* W4 = (const float*)d_in[9]; const float* b4 = (const float*)d_in[10];
    float* out = (float*)d_out;

    const size_t need = (size_t)3 * 512 * 512 * sizeof(f16);
    if (ws_size >= need) {
        f16* wp = (f16*)d_ws;
        prep_w<<<(3 * 16 * 32 * 64 + 255) / 256, 256, 0, stream>>>(W1, W2, W3, wp);
        mlp_fused<true><<<NBLK, 512, 0, stream>>>(tx, W0, b0, W1, b1, W2, b2, W3, b3, W4, b4, wp, out);
    } else {
        mlp_fused<false><<<NBLK, 512, 0, stream>>>(tx, W0, b0, W1, b1, W2, b2, W3, b3, W4, b4, nullptr, out);
    }
}

// Round 5
// 980.853 us; speedup vs baseline: 1.5131x; 1.5131x over previous
//
#include <hip/hip_runtime.h>

typedef _Float16 f16;
typedef __attribute__((ext_vector_type(8))) _Float16 f16x8;
typedef __attribute__((ext_vector_type(4))) float f32x4;

#define BT   131072
#define DD   512
#define TM   32
#define MEFF 96
#define NBLK (BT / TM)  // 4096

__device__ __forceinline__ float softplus20(float z) {
    // softplus(20z)/20 = max(z,0) + log1p(exp(-20|z|))/20
    float a = fabsf(z);
    float e = __expf(-20.f * a);
    return fmaxf(z, 0.f) + __logf(1.f + e) * 0.05f;
}

// swizzled LDS fp16 tile: byte = row*1024 + (colbyte ^ ((row&7)<<4))
__device__ __forceinline__ void stA(char* ab, int row, int colbyte, float v) {
    *(f16*)(ab + row * 1024 + (colbyte ^ ((row & 7) << 4))) = (f16)v;
}
__device__ __forceinline__ f16x8 ldA8(const char* ab, int row, int kbyte) {
    return *(const f16x8*)(ab + row * 1024 + (kbyte ^ ((row & 7) << 4)));
}

// Pack W1..W3 (512x512 fp32 row-major) into MFMA B-fragment order fp16:
// frag f = (l*16+sk)*32 + nsub ; lane l: n = nsub*16+(lane&15), k = sk*32+(lane>>4)*8 .. +8
__global__ void prep_w(const float* __restrict__ W1, const float* __restrict__ W2,
                       const float* __restrict__ W3, f16* __restrict__ wp) {
    int tid = blockIdx.x * 256 + threadIdx.x;
    if (tid >= 3 * 16 * 32 * 64) return;
    int lane = tid & 63;
    int frag = tid >> 6;
    int nsub = frag & 31;
    int sk   = (frag >> 5) & 15;
    int l    = frag >> 9;
    const float* W = (l == 0) ? W1 : (l == 1) ? W2 : W3;
    int n = nsub * 16 + (lane & 15);
    int k = sk * 32 + (lane >> 4) * 8;
    const float* p = W + n * DD + k;
    f16x8 o;
    #pragma unroll
    for (int j = 0; j < 8; ++j) o[j] = (f16)p[j];
    ((f16x8*)wp)[tid] = o;
}

template<bool PREP>
__global__ __launch_bounds__(512)
__attribute__((amdgpu_waves_per_eu(1, 2)))  // budget 512/2 = 256 regs/wave; LDS caps us at 2 waves/EU anyway
void mlp_fused(
    const float* __restrict__ tx,
    const float* __restrict__ W0, const float* __restrict__ b0v,
    const float* __restrict__ W1, const float* __restrict__ b1v,
    const float* __restrict__ W2, const float* __restrict__ b2v,
    const float* __restrict__ W3, const float* __restrict__ b3v,
    const float* __restrict__ W4, const float* __restrict__ b4v,
    const f16* __restrict__ wp, float* __restrict__ out)
{
    __shared__ __align__(16) short abuf_s[MEFF * DD];  // 96 KB fp16, swizzled
    __shared__ float txb[TM * 3];
    char* ab = (char*)abuf_s;

    const int tid  = threadIdx.x;
    const int lane = tid & 63;
    const int wv   = tid >> 6;   // 0..7, owns cols [wv*64, wv*64+64)
    const int g16  = lane >> 4;
    const int l15  = lane & 15;
    const long s0  = (long)blockIdx.x * TM;

    if (tid < TM * 3) txb[tid] = tx[s0 * 3 + tid];
    __syncthreads();

    // ---- layer 0: z1 = W0 x + b0 (K=3, fp32 VALU); rows: h | sg*W0[:,1] | sg*W0[:,2]
    {
        int n = tid;  // one output neuron per thread
        float w0 = W0[n * 3 + 0], w1 = W0[n * 3 + 1], w2 = W0[n * 3 + 2], bb = b0v[n];
        #pragma unroll 4
        for (int s = 0; s < TM; ++s) {
            float z = fmaf(w0, txb[s * 3], fmaf(w1, txb[s * 3 + 1], fmaf(w2, txb[s * 3 + 2], bb)));
            float h = softplus20(z);
            float sg = 1.f - __expf(-20.f * h);  // sigmoid(20z) via softplus inverse
            stA(ab, s,          n * 2, h);
            stA(ab, TM + s,     n * 2, sg * w1);
            stA(ab, 2 * TM + s, n * 2, sg * w2);
        }
    }
    __syncthreads();

    float sgr[2][4][4];  // sigma regs: [h-msub][nsub][r]

    // ---- layers 1..3: fused GEMM over M_eff=96 rows (h + 2 tangents), N=K=512
    for (int l = 0; l < 3; ++l) {
        const float* Wl = (l == 0) ? W1 : (l == 1) ? W2 : W3;
        const float* bl = (l == 0) ? b1v : (l == 1) ? b2v : b3v;
        const f16x8* wpb = (const f16x8*)wp + (size_t)l * 16 * 32 * 64;

        f32x4 acc[6][4];
        #pragma unroll
        for (int m = 0; m < 6; ++m)
            #pragma unroll
            for (int n = 0; n < 4; ++n)
                acc[m][n] = f32x4{0.f, 0.f, 0.f, 0.f};

        auto loadB = [&](f16x8* dst, int sk) {
            if constexpr (PREP) {
                const f16x8* p = wpb + (size_t)(sk * 32 + wv * 4) * 64 + lane;
                #pragma unroll
                for (int n = 0; n < 4; ++n) dst[n] = p[n * 64];
            } else {
                #pragma unroll
                for (int n = 0; n < 4; ++n) {
                    const float* q = Wl + (size_t)(wv * 64 + n * 16 + l15) * DD + sk * 32 + g16 * 8;
                    float4 u0 = *(const float4*)q;
                    float4 u1 = *(const float4*)(q + 4);
                    f16x8 r;
                    r[0] = (f16)u0.x; r[1] = (f16)u0.y; r[2] = (f16)u0.z; r[3] = (f16)u0.w;
                    r[4] = (f16)u1.x; r[5] = (f16)u1.y; r[6] = (f16)u1.z; r[7] = (f16)u1.w;
                    dst[n] = r;
                }
            }
        };
        // A fragments loaded per-m and consumed immediately (short LDS latency,
        // covered by lgkmcnt + TLP). Only B (L2 stream) is double-buffered.
        auto domfma = [&](const f16x8* bf, int sk) {
            #pragma unroll
            for (int m = 0; m < 6; ++m) {
                f16x8 a = ldA8(ab, m * 16 + l15, sk * 64 + g16 * 16);
                #pragma unroll
                for (int n = 0; n < 4; ++n)
                    acc[m][n] = __builtin_amdgcn_mfma_f32_16x16x32_f16(a, bf[n], acc[m][n], 0, 0, 0);
            }
        };

        f16x8 bf0[4], bf1[4];
        loadB(bf0, 0);
        for (int sk = 0; sk < 16; sk += 2) {
            loadB(bf1, sk + 1);
            domfma(bf0, sk);
            if (sk + 2 < 16) loadB(bf0, sk + 2);
            domfma(bf1, sk + 1);
        }

        __syncthreads();  // all waves done reading abuf

        float bias[4];
        #pragma unroll
        for (int n = 0; n < 4; ++n) bias[n] = bl[wv * 64 + n * 16 + l15];

        // h rows (msub 0,1): z -> h -> LDS ; sigma -> regs
        #pragma unroll
        for (int m = 0; m < 2; ++m)
            #pragma unroll
            for (int n = 0; n < 4; ++n)
                #pragma unroll
                for (int r = 0; r < 4; ++r) {
                    int row = m * 16 + g16 * 4 + r;
                    float z = acc[m][n][r] + bias[n];
                    float h = softplus20(z);
                    sgr[m][n][r] = 1.f - __expf(-20.f * h);
                    stA(ab, row, (wv * 64 + n * 16 + l15) * 2, h);
                }
        // tangent rows (msub 2..5): hdot = sigma * zdot  (no bias). Same lane/reg as its h.
        #pragma unroll
        for (int m = 2; m < 6; ++m)
            #pragma unroll
            for (int n = 0; n < 4; ++n)
                #pragma unroll
                for (int r = 0; r < 4; ++r) {
                    int row = m * 16 + g16 * 4 + r;
                    float v = sgr[m & 1][n][r] * acc[m][n][r];
                    stA(ab, row, (wv * 64 + n * 16 + l15) * 2, v);
                }
        __syncthreads();
    }

    // ---- final layer (fp32 VALU dots): p = W4[1].h4 + b4[1]; u = (ds/dy, -ds/dx)
    {
        const int kb = lane * 8;
        float wsr[8], wpr[8];
        #pragma unroll
        for (int j = 0; j < 8; ++j) { wsr[j] = W4[kb + j]; wpr[j] = W4[DD + kb + j]; }
        float bp = b4v[1];
        #pragma unroll
        for (int i = 0; i < 4; ++i) {
            int s = wv * 4 + i;
            f16x8 hh = ldA8(ab, s,      lane * 16);
            f16x8 hx = ldA8(ab, 32 + s, lane * 16);
            f16x8 hy = ldA8(ab, 64 + s, lane * 16);
            float dy = 0.f, dx = 0.f, dp = 0.f;
            #pragma unroll
            for (int j = 0; j < 8; ++j) {
                dy = fmaf(wsr[j], (float)hy[j], dy);
                dx = fmaf(wsr[j], (float)hx[j], dx);
                dp = fmaf(wpr[j], (float)hh[j], dp);
            }
            #pragma unroll
            for (int mk = 1; mk < 64; mk <<= 1) {
                dy += __shfl_xor(dy, mk);
                dx += __shfl_xor(dx, mk);
                dp += __shfl_xor(dp, mk);
            }
            if (lane == 0) {
                float* o = out + (s0 + s) * 3;
                o[0] = dy;        // ds/dy
                o[1] = -dx;       // -ds/dx
                o[2] = dp + bp;   // pressure
            }
        }
    }
}

extern "C" void kernel_launch(void* const* d_in, const int* in_sizes, int n_in,
                              void* d_out, int out_size, void* d_ws, size_t ws_size,
                              hipStream_t stream) {
    const float* tx = (const float*)d_in[0];
    const float* W0 = (const float*)d_in[1]; const float* b0 = (const float*)d_in[2];
    const float* W1 = (const float*)d_in[3]; const float* b1 = (const float*)d_in[4];
    const float* W2 = (const float*)d_in[5]; const float* b2 = (const float*)d_in[6];
    const float* W3 = (const float*)d_in[7]; const float* b3 = (const float*)d_in[8];
    const float* W4 = (const float*)d_in[9]; const float* b4 = (const float*)d_in[10];
    float* out = (float*)d_out;

    const size_t need = (size_t)3 * 512 * 512 * sizeof(f16);
    if (ws_size >= need) {
        f16* wp = (f16*)d_ws;
        prep_w<<<(3 * 16 * 32 * 64 + 255) / 256, 256, 0, stream>>>(W1, W2, W3, wp);
        mlp_fused<true><<<NBLK, 512, 0, stream>>>(tx, W0, b0, W1, b1, W2, b2, W3, b3, W4, b4, wp, out);
    } else {
        mlp_fused<false><<<NBLK, 512, 0, stream>>>(tx, W0, b0, W1, b1, W2, b2, W3, b3, W4, b4, nullptr, out);
    }
}

// Round 6
// 772.251 us; speedup vs baseline: 1.9219x; 1.2701x over previous
//
#include <hip/hip_runtime.h>

typedef _Float16 f16;
typedef __attribute__((ext_vector_type(8))) _Float16 f16x8;
typedef __attribute__((ext_vector_type(4))) float f32x4;

#define BT   131072
#define DD   512
#define TM   32
#define MEFF 96
#define NBLK (BT / TM)  // 4096

// swizzled LDS fp16 tile: byte = row*1024 + (colbyte ^ ((row&7)<<4))
__device__ __forceinline__ void stA(char* ab, int row, int colbyte, float v) {
    *(f16*)(ab + row * 1024 + (colbyte ^ ((row & 7) << 4))) = (f16)v;
}
__device__ __forceinline__ f16x8 ldA8(const char* ab, int row, int kbyte) {
    return *(const f16x8*)(ab + row * 1024 + (kbyte ^ ((row & 7) << 4)));
}

__device__ __forceinline__ f16x8 cvt8(const float* q) {
    float4 u0 = *(const float4*)q;
    float4 u1 = *(const float4*)(q + 4);
    f16x8 r;
    r[0] = (f16)u0.x; r[1] = (f16)u0.y; r[2] = (f16)u0.z; r[3] = (f16)u0.w;
    r[4] = (f16)u1.x; r[5] = (f16)u1.y; r[6] = (f16)u1.z; r[7] = (f16)u1.w;
    return r;
}

// Pack W1..W3 (512x512 fp32 row-major) into MFMA B-fragment order fp16:
// frag f = (l*16+sk)*32 + nsub ; lane l: n = nsub*16+(lane&15), k = sk*32+(lane>>4)*8 .. +8
__global__ void prep_w(const float* __restrict__ W1, const float* __restrict__ W2,
                       const float* __restrict__ W3, f16* __restrict__ wp) {
    int tid = blockIdx.x * 256 + threadIdx.x;
    if (tid >= 3 * 16 * 32 * 64) return;
    int lane = tid & 63;
    int frag = tid >> 6;
    int nsub = frag & 31;
    int sk   = (frag >> 5) & 15;
    int l    = frag >> 9;
    const float* W = (l == 0) ? W1 : (l == 1) ? W2 : W3;
    int n = nsub * 16 + (lane & 15);
    int k = sk * 32 + (lane >> 4) * 8;
    ((f16x8*)wp)[tid] = cvt8(W + n * DD + k);
}

template<bool PREP>
__global__ __launch_bounds__(512) void mlp_fused(
    const float* __restrict__ tx,
    const float* __restrict__ W0, const float* __restrict__ b0v,
    const float* __restrict__ W1, const float* __restrict__ b1v,
    const float* __restrict__ W2, const float* __restrict__ b2v,
    const float* __restrict__ W3, const float* __restrict__ b3v,
    const float* __restrict__ W4, const float* __restrict__ b4v,
    const f16* __restrict__ wp, float* __restrict__ out)
{
    __shared__ __align__(16) short abuf_s[MEFF * DD];  // 96 KB fp16, swizzled
    __shared__ float txb[TM * 3];
    char* ab = (char*)abuf_s;

    const int tid  = threadIdx.x;
    const int lane = tid & 63;
    const int wv   = tid >> 6;   // 0..7, owns cols [wv*64, wv*64+64)
    const int g16  = lane >> 4;
    const int l15  = lane & 15;
    const long s0  = (long)blockIdx.x * TM;

    if (tid < TM * 3) txb[tid] = tx[s0 * 3 + tid];
    __syncthreads();

    // ---- layer 0: z1 = W0 x + b0 (K=3, fp32 VALU); rows: h | sg*W0[:,1] | sg*W0[:,2]
    {
        int n = tid;
        float w0 = W0[n * 3 + 0], w1 = W0[n * 3 + 1], w2 = W0[n * 3 + 2], bb = b0v[n];
        #pragma unroll 4
        for (int s = 0; s < TM; ++s) {
            float z  = fmaf(w0, txb[s * 3], fmaf(w1, txb[s * 3 + 1], fmaf(w2, txb[s * 3 + 2], bb)));
            float aa = fabsf(z);
            float e  = __expf(-20.f * aa);
            float dd = 1.f + e;
            float h  = fmaxf(z, 0.f) + __logf(dd) * 0.05f;
            float sg = (z > 0.f ? 1.f : e) * __builtin_amdgcn_rcpf(dd);
            stA(ab, s,          n * 2, h);
            stA(ab, TM + s,     n * 2, sg * w1);
            stA(ab, 2 * TM + s, n * 2, sg * w2);
        }
    }
    __syncthreads();

    // ---- layers 1..3: fused GEMM over M_eff=96 rows (h + 2 tangents), N=K=512
    // Arch-VGPR discipline (rounds 1-5 lesson: arch budget is 128, overflow
    // goes to scratch = 378 MB HBM traffic): single-buffered B (16 regs),
    // A-frag transient, no sigma register array, unroll capped at 2.
    for (int l = 0; l < 3; ++l) {
        const float* Wl = (l == 0) ? W1 : (l == 1) ? W2 : W3;
        const float* bl = (l == 0) ? b1v : (l == 1) ? b2v : b3v;
        const f16x8* wB = (const f16x8*)wp + (size_t)l * (16 * 32 * 64)
                        + (size_t)(wv * 4) * 64 + lane;

        f32x4 acc[6][4];
        #pragma unroll
        for (int m = 0; m < 6; ++m)
            #pragma unroll
            for (int n = 0; n < 4; ++n)
                acc[m][n] = f32x4{0.f, 0.f, 0.f, 0.f};

        #pragma unroll 2
        for (int sk = 0; sk < 16; ++sk) {
            f16x8 b0, b1, b2, b3;
            if constexpr (PREP) {
                const f16x8* p = wB + (size_t)(sk * 32) * 64;
                b0 = p[0]; b1 = p[64]; b2 = p[128]; b3 = p[192];
            } else {
                const float* q = Wl + (size_t)(wv * 64 + l15) * DD + sk * 32 + g16 * 8;
                b0 = cvt8(q);
                b1 = cvt8(q + 16 * DD);
                b2 = cvt8(q + 32 * DD);
                b3 = cvt8(q + 48 * DD);
            }
            #pragma unroll
            for (int m = 0; m < 6; ++m) {
                f16x8 a = ldA8(ab, m * 16 + l15, sk * 64 + g16 * 16);
                acc[m][0] = __builtin_amdgcn_mfma_f32_16x16x32_f16(a, b0, acc[m][0], 0, 0, 0);
                acc[m][1] = __builtin_amdgcn_mfma_f32_16x16x32_f16(a, b1, acc[m][1], 0, 0, 0);
                acc[m][2] = __builtin_amdgcn_mfma_f32_16x16x32_f16(a, b2, acc[m][2], 0, 0, 0);
                acc[m][3] = __builtin_amdgcn_mfma_f32_16x16x32_f16(a, b3, acc[m][3], 0, 0, 0);
            }
        }

        __syncthreads();  // all waves done reading abuf

        // fused epilogue: per element compute h,sigma inline and write all
        // three rows (h, sg*xdot, sg*ydot). No sigma register array.
        #pragma unroll
        for (int m = 0; m < 2; ++m)
            #pragma unroll
            for (int n = 0; n < 4; ++n) {
                float bias = bl[wv * 64 + n * 16 + l15];
                int   cb   = (wv * 64 + n * 16 + l15) * 2;
                #pragma unroll
                for (int r = 0; r < 4; ++r) {
                    int row = m * 16 + g16 * 4 + r;
                    float z  = acc[m][n][r] + bias;
                    float aa = fabsf(z);
                    float e  = __expf(-20.f * aa);
                    float dd = 1.f + e;
                    float h  = fmaxf(z, 0.f) + __logf(dd) * 0.05f;
                    float sg = (z > 0.f ? 1.f : e) * __builtin_amdgcn_rcpf(dd);
                    stA(ab, row,      cb, h);
                    stA(ab, row + 32, cb, sg * acc[m + 2][n][r]);
                    stA(ab, row + 64, cb, sg * acc[m + 4][n][r]);
                }
            }
        __syncthreads();
    }

    // ---- final layer (fp32 VALU dots): p = W4[1].h4 + b4[1]; u = (ds/dy, -ds/dx)
    {
        const int kb = lane * 8;
        float wsr[8], wpr[8];
        #pragma unroll
        for (int j = 0; j < 8; ++j) { wsr[j] = W4[kb + j]; wpr[j] = W4[DD + kb + j]; }
        float bp = b4v[1];
        #pragma unroll
        for (int i = 0; i < 4; ++i) {
            int s = wv * 4 + i;
            f16x8 hh = ldA8(ab, s,      lane * 16);
            f16x8 hx = ldA8(ab, 32 + s, lane * 16);
            f16x8 hy = ldA8(ab, 64 + s, lane * 16);
            float dy = 0.f, dx = 0.f, dp = 0.f;
            #pragma unroll
            for (int j = 0; j < 8; ++j) {
                dy = fmaf(wsr[j], (float)hy[j], dy);
                dx = fmaf(wsr[j], (float)hx[j], dx);
                dp = fmaf(wpr[j], (float)hh[j], dp);
            }
            #pragma unroll
            for (int mk = 1; mk < 64; mk <<= 1) {
                dy += __shfl_xor(dy, mk);
                dx += __shfl_xor(dx, mk);
                dp += __shfl_xor(dp, mk);
            }
            if (lane == 0) {
                float* o = out + (s0 + s) * 3;
                o[0] = dy;        // ds/dy
                o[1] = -dx;       // -ds/dx
                o[2] = dp + bp;   // pressure
            }
        }
    }
}

extern "C" void kernel_launch(void* const* d_in, const int* in_sizes, int n_in,
                              void* d_out, int out_size, void* d_ws, size_t ws_size,
                              hipStream_t stream) {
    const float* tx = (const float*)d_in[0];
    const float* W0 = (const float*)d_in[1]; const float* b0 = (const float*)d_in[2];
    const float* W1 = (const float*)d_in[3]; const float* b1 = (const float*)d_in[4];
    const float* W2 = (const float*)d_in[5]; const float* b2 = (const float*)d_in[6];
    const float* W3 = (const float*)d_in[7]; const float* b3 = (const float*)d_in[8];
    const float* W4 = (const float*)d_in[9]; const float* b4 = (const float*)d_in[10];
    float* out = (float*)d_out;

    const size_t need = (size_t)3 * 512 * 512 * sizeof(f16);
    if (ws_size >= need) {
        f16* wp = (f16*)d_ws;
        prep_w<<<(3 * 16 * 32 * 64 + 255) / 256, 256, 0, stream>>>(W1, W2, W3, wp);
        mlp_fused<true><<<NBLK, 512, 0, stream>>>(tx, W0, b0, W1, b1, W2, b2, W3, b3, W4, b4, wp, out);
    } else {
        mlp_fused<false><<<NBLK, 512, 0, stream>>>(tx, W0, b0, W1, b1, W2, b2, W3, b3, W4, b4, nullptr, out);
    }
}

// Round 7
// 758.808 us; speedup vs baseline: 1.9559x; 1.0177x over previous
//
#include <hip/hip_runtime.h>

typedef _Float16 f16;
typedef __attribute__((ext_vector_type(8))) _Float16 f16x8;
typedef __attribute__((ext_vector_type(4))) float f32x4;

#define BT   131072
#define DD   512
#define TM   32
#define MEFF 96
#define NBLK (BT / TM)  // 4096

// swizzled LDS fp16 tile: byte = row*1024 + (colbyte ^ ((row&7)<<4))
__device__ __forceinline__ void stA(char* ab, int row, int colbyte, float v) {
    *(f16*)(ab + row * 1024 + (colbyte ^ ((row & 7) << 4))) = (f16)v;
}
__device__ __forceinline__ f16x8 ldA8(const char* ab, int row, int kbyte) {
    return *(const f16x8*)(ab + row * 1024 + (kbyte ^ ((row & 7) << 4)));
}

__device__ __forceinline__ f16x8 cvt8(const float* q) {
    float4 u0 = *(const float4*)q;
    float4 u1 = *(const float4*)(q + 4);
    f16x8 r;
    r[0] = (f16)u0.x; r[1] = (f16)u0.y; r[2] = (f16)u0.z; r[3] = (f16)u0.w;
    r[4] = (f16)u1.x; r[5] = (f16)u1.y; r[6] = (f16)u1.z; r[7] = (f16)u1.w;
    return r;
}

// Pack W1..W3 (512x512 fp32 row-major) into MFMA B-fragment order fp16:
// frag f = (l*16+sk)*32 + nsub ; lane l: n = nsub*16+(lane&15), k = sk*32+(lane>>4)*8 .. +8
__global__ void prep_w(const float* __restrict__ W1, const float* __restrict__ W2,
                       const float* __restrict__ W3, f16* __restrict__ wp) {
    int tid = blockIdx.x * 256 + threadIdx.x;
    if (tid >= 3 * 16 * 32 * 64) return;
    int lane = tid & 63;
    int frag = tid >> 6;
    int nsub = frag & 31;
    int sk   = (frag >> 5) & 15;
    int l    = frag >> 9;
    const float* W = (l == 0) ? W1 : (l == 1) ? W2 : W3;
    int n = nsub * 16 + (lane & 15);
    int k = sk * 32 + (lane >> 4) * 8;
    ((f16x8*)wp)[tid] = cvt8(W + n * DD + k);
}

// 6 ds_read + 24 MFMA for one k-slice sk, B frags given as named regs.
#define MFMA_SK(skc, Q0, Q1, Q2, Q3)                                           \
    _Pragma("unroll")                                                          \
    for (int m = 0; m < 6; ++m) {                                              \
        f16x8 a = ldA8(ab, m * 16 + l15, (skc) * 64 + g16 * 16);               \
        acc[m][0] = __builtin_amdgcn_mfma_f32_16x16x32_f16(a, Q0, acc[m][0], 0, 0, 0); \
        acc[m][1] = __builtin_amdgcn_mfma_f32_16x16x32_f16(a, Q1, acc[m][1], 0, 0, 0); \
        acc[m][2] = __builtin_amdgcn_mfma_f32_16x16x32_f16(a, Q2, acc[m][2], 0, 0, 0); \
        acc[m][3] = __builtin_amdgcn_mfma_f32_16x16x32_f16(a, Q3, acc[m][3], 0, 0, 0); \
    }

#define LOADB(Q0, Q1, Q2, Q3, skc)                                             \
    if constexpr (PREP) {                                                      \
        const f16x8* p = wB + (size_t)((skc) * 32) * 64;                       \
        Q0 = p[0]; Q1 = p[64]; Q2 = p[128]; Q3 = p[192];                       \
    } else {                                                                   \
        const float* q = Wl + (size_t)(wv * 64 + l15) * DD + (skc) * 32 + g16 * 8; \
        Q0 = cvt8(q);                                                          \
        Q1 = cvt8(q + 16 * DD);                                                \
        Q2 = cvt8(q + 32 * DD);                                                \
        Q3 = cvt8(q + 48 * DD);                                                \
    }

template<bool PREP>
__global__ __launch_bounds__(512) void mlp_fused(
    const float* __restrict__ tx,
    const float* __restrict__ W0, const float* __restrict__ b0v,
    const float* __restrict__ W1, const float* __restrict__ b1v,
    const float* __restrict__ W2, const float* __restrict__ b2v,
    const float* __restrict__ W3, const float* __restrict__ b3v,
    const float* __restrict__ W4, const float* __restrict__ b4v,
    const f16* __restrict__ wp, float* __restrict__ out)
{
    __shared__ __align__(16) short abuf_s[MEFF * DD];  // 96 KB fp16, swizzled
    __shared__ float txb[TM * 3];
    char* ab = (char*)abuf_s;

    const int tid  = threadIdx.x;
    const int lane = tid & 63;
    const int wv   = tid >> 6;   // 0..7, owns cols [wv*64, wv*64+64)
    const int g16  = lane >> 4;
    const int l15  = lane & 15;
    const long s0  = (long)blockIdx.x * TM;

    if (tid < TM * 3) txb[tid] = tx[s0 * 3 + tid];
    __syncthreads();

    // ---- layer 0: z1 = W0 x + b0 (K=3, fp32 VALU); rows: h | sg*W0[:,1] | sg*W0[:,2]
    {
        int n = tid;
        float w0 = W0[n * 3 + 0], w1 = W0[n * 3 + 1], w2 = W0[n * 3 + 2], bb = b0v[n];
        #pragma unroll 4
        for (int s = 0; s < TM; ++s) {
            float z  = fmaf(w0, txb[s * 3], fmaf(w1, txb[s * 3 + 1], fmaf(w2, txb[s * 3 + 2], bb)));
            float aa = fabsf(z);
            float e  = __expf(-20.f * aa);
            float dd = 1.f + e;
            float h  = fmaxf(z, 0.f) + __logf(dd) * 0.05f;
            float sg = (z > 0.f ? 1.f : e) * __builtin_amdgcn_rcpf(dd);
            stA(ab, s,          n * 2, h);
            stA(ab, TM + s,     n * 2, sg * w1);
            stA(ab, 2 * TM + s, n * 2, sg * w2);
        }
    }
    __syncthreads();

    // ---- layers 1..3: fused GEMM over M_eff=96 rows (h + 2 tangents), N=K=512
    // Arch-VGPR discipline (rounds 1-6): named B regs only, no arrays/lambdas,
    // sk-loop unroll 2. Round-6 baseline (single-buffer) = 772 us, latency-
    // exposed on the per-sk vmcnt(0); this version double-buffers B in 8 named
    // f16x8 (+16 arch regs, ~112 < 128 budget) so loads for sk+1 are in flight
    // during sk's 24 MFMAs (counted vmcnt, never drain-0 in steady state).
    for (int l = 0; l < 3; ++l) {
        const float* Wl = (l == 0) ? W1 : (l == 1) ? W2 : W3;
        const float* bl = (l == 0) ? b1v : (l == 1) ? b2v : b3v;
        const f16x8* wB = (const f16x8*)wp + (size_t)l * (16 * 32 * 64)
                        + (size_t)(wv * 4) * 64 + lane;

        f32x4 acc[6][4];
        #pragma unroll
        for (int m = 0; m < 6; ++m)
            #pragma unroll
            for (int n = 0; n < 4; ++n)
                acc[m][n] = f32x4{0.f, 0.f, 0.f, 0.f};

        f16x8 B0, B1, B2, B3, C0, C1, C2, C3;
        LOADB(B0, B1, B2, B3, 0)
        #pragma unroll 2
        for (int sk = 0; sk < 16; sk += 2) {
            LOADB(C0, C1, C2, C3, sk + 1)
            MFMA_SK(sk, B0, B1, B2, B3)
            if (sk + 2 < 16) { LOADB(B0, B1, B2, B3, sk + 2) }
            MFMA_SK(sk + 1, C0, C1, C2, C3)
        }

        __syncthreads();  // all waves done reading abuf

        // fused epilogue: per element compute h,sigma inline and write all
        // three rows (h, sg*xdot, sg*ydot). No sigma register array.
        #pragma unroll
        for (int m = 0; m < 2; ++m)
            #pragma unroll
            for (int n = 0; n < 4; ++n) {
                float bias = bl[wv * 64 + n * 16 + l15];
                int   cb   = (wv * 64 + n * 16 + l15) * 2;
                #pragma unroll
                for (int r = 0; r < 4; ++r) {
                    int row = m * 16 + g16 * 4 + r;
                    float z  = acc[m][n][r] + bias;
                    float aa = fabsf(z);
                    float e  = __expf(-20.f * aa);
                    float dd = 1.f + e;
                    float h  = fmaxf(z, 0.f) + __logf(dd) * 0.05f;
                    float sg = (z > 0.f ? 1.f : e) * __builtin_amdgcn_rcpf(dd);
                    stA(ab, row,      cb, h);
                    stA(ab, row + 32, cb, sg * acc[m + 2][n][r]);
                    stA(ab, row + 64, cb, sg * acc[m + 4][n][r]);
                }
            }
        __syncthreads();
    }

    // ---- final layer (fp32 VALU dots): p = W4[1].h4 + b4[1]; u = (ds/dy, -ds/dx)
    {
        const int kb = lane * 8;
        float wsr[8], wpr[8];
        #pragma unroll
        for (int j = 0; j < 8; ++j) { wsr[j] = W4[kb + j]; wpr[j] = W4[DD + kb + j]; }
        float bp = b4v[1];
        #pragma unroll
        for (int i = 0; i < 4; ++i) {
            int s = wv * 4 + i;
            f16x8 hh = ldA8(ab, s,      lane * 16);
            f16x8 hx = ldA8(ab, 32 + s, lane * 16);
            f16x8 hy = ldA8(ab, 64 + s, lane * 16);
            float dy = 0.f, dx = 0.f, dp = 0.f;
            #pragma unroll
            for (int j = 0; j < 8; ++j) {
                dy = fmaf(wsr[j], (float)hy[j], dy);
                dx = fmaf(wsr[j], (float)hx[j], dx);
                dp = fmaf(wpr[j], (float)hh[j], dp);
            }
            #pragma unroll
            for (int mk = 1; mk < 64; mk <<= 1) {
                dy += __shfl_xor(dy, mk);
                dx += __shfl_xor(dx, mk);
                dp += __shfl_xor(dp, mk);
            }
            if (lane == 0) {
                float* o = out + (s0 + s) * 3;
                o[0] = dy;        // ds/dy
                o[1] = -dx;       // -ds/dx
                o[2] = dp + bp;   // pressure
            }
        }
    }
}

extern "C" void kernel_launch(void* const* d_in, const int* in_sizes, int n_in,
                              void* d_out, int out_size, void* d_ws, size_t ws_size,
                              hipStream_t stream) {
    const float* tx = (const float*)d_in[0];
    const float* W0 = (const float*)d_in[1]; const float* b0 = (const float*)d_in[2];
    const float* W1 = (const float*)d_in[3]; const float* b1 = (const float*)d_in[4];
    const float* W2 = (const float*)d_in[5]; const float* b2 = (const float*)d_in[6];
    const float* W3 = (const float*)d_in[7]; const float* b3 = (const float*)d_in[8];
    const float* W4 = (const float*)d_in[9]; const float* b4 = (const float*)d_in[10];
    float* out = (float*)d_out;

    const size_t need = (size_t)3 * 512 * 512 * sizeof(f16);
    if (ws_size >= need) {
        f16* wp = (f16*)d_ws;
        prep_w<<<(3 * 16 * 32 * 64 + 255) / 256, 256, 0, stream>>>(W1, W2, W3, wp);
        mlp_fused<true><<<NBLK, 512, 0, stream>>>(tx, W0, b0, W1, b1, W2, b2, W3, b3, W4, b4, wp, out);
    } else {
        mlp_fused<false><<<NBLK, 512, 0, stream>>>(tx, W0, b0, W1, b1, W2, b2, W3, b3, W4, b4, nullptr, out);
    }
}